// Round 1
// baseline (155.499 us; speedup 1.0000x reference)
//
#include <hip/hip_runtime.h>
#include <math.h>

// ---------------------------------------------------------------------------
// UnitingModelForNLP: h = tanh(x0 @ pu0^T + bdb); out = h @ pu1^T + bob
// pu = unite(p_i, p_j, W, b):
//   w_local = sigmoid(|p_i-p_j| @ W^T + b)
//   w_global = 0.4/pi * atan(500*(H(p_i)-H(p_j))) + 0.5   (10-bin histogram entropy)
//   w = wg*w_local + (1-wg);  pu = p_i*w + p_j*(1-w)
// Workspace layout (floats/uints):
//   [0..7]   encoded min/max for 4 matrices
//   [8..47]  histograms 4 x 10 (uint)
//   [48]=wg0 [49]=wg1
//   [64 ..)              pu0      (1024*1024 f32)
//   (+1048576)           hpart    (8*64*1024 f32)
//   (+524288)            h        (64*1024 f32)
//   (+65536)             pu1      (3*1024 f32)
// Total ~6.6 MB of d_ws.
// ---------------------------------------------------------------------------

#define NBINS 10

static __device__ __forceinline__ unsigned enc_f(float x) {
    unsigned u = __float_as_uint(x);
    return (u & 0x80000000u) ? ~u : (u | 0x80000000u);
}
static __device__ __forceinline__ float dec_f(unsigned u) {
    u = (u & 0x80000000u) ? (u & 0x7FFFFFFFu) : ~u;
    return __uint_as_float(u);
}

__global__ void k_init(unsigned* ws_u) {
    int t = threadIdx.x;
    if (t < 8)  ws_u[t] = (t & 1) ? 0u : 0xFFFFFFFFu;  // min slots=UINT_MAX, max slots=0
    if (t >= 8 && t < 48) ws_u[t] = 0u;
}

// blockIdx.y selects matrix: 0=bdw 1=gdw 2=bow 3=gow
__global__ void k_minmax(const float* __restrict__ a0, const float* __restrict__ a1,
                         const float* __restrict__ a2, const float* __restrict__ a3,
                         unsigned* __restrict__ ws_u) {
    int m = blockIdx.y;
    const float* p = (m == 0) ? a0 : (m == 1) ? a1 : (m == 2) ? a2 : a3;
    int n = (m < 2) ? 1024 * 1024 : 3 * 1024;
    float lo = INFINITY, hi = -INFINITY;
    for (int i = blockIdx.x * blockDim.x + threadIdx.x; i < n; i += gridDim.x * blockDim.x) {
        float v = p[i];
        lo = fminf(lo, v);
        hi = fmaxf(hi, v);
    }
    for (int off = 32; off; off >>= 1) {
        lo = fminf(lo, __shfl_down(lo, off));
        hi = fmaxf(hi, __shfl_down(hi, off));
    }
    __shared__ float slo[4], shi[4];
    int wid = threadIdx.x >> 6;
    if ((threadIdx.x & 63) == 0) { slo[wid] = lo; shi[wid] = hi; }
    __syncthreads();
    if (threadIdx.x == 0) {
        for (int w = 1; w < (int)(blockDim.x >> 6); w++) { lo = fminf(lo, slo[w]); hi = fmaxf(hi, shi[w]); }
        atomicMin(&ws_u[2 * m], enc_f(lo));
        atomicMax(&ws_u[2 * m + 1], enc_f(hi));
    }
}

__global__ void k_hist(const float* __restrict__ a0, const float* __restrict__ a1,
                       const float* __restrict__ a2, const float* __restrict__ a3,
                       unsigned* __restrict__ ws_u) {
    int m = blockIdx.y;
    const float* p = (m == 0) ? a0 : (m == 1) ? a1 : (m == 2) ? a2 : a3;
    int n = (m < 2) ? 1024 * 1024 : 3 * 1024;
    float lo = dec_f(ws_u[2 * m]);
    float hi = dec_f(ws_u[2 * m + 1]);
    // exact f32 arithmetic, no contraction: scale=(hi-lo)/10; lower=lo+i*scale; upper=lower+scale
    float scale = __fdiv_rn(__fsub_rn(hi, lo), 10.0f);
    float lower[NBINS], upper[NBINS];
#pragma unroll
    for (int b = 0; b < NBINS; b++) {
        lower[b] = __fadd_rn(lo, __fmul_rn((float)b, scale));
        upper[b] = __fadd_rn(lower[b], scale);
    }
    unsigned cnt[NBINS] = {};
    for (int i = blockIdx.x * blockDim.x + threadIdx.x; i < n; i += gridDim.x * blockDim.x) {
        float v = p[i];
#pragma unroll
        for (int b = 0; b < NBINS; b++)
            if (v >= lower[b] && v < upper[b]) cnt[b]++;
    }
    __shared__ unsigned sh[NBINS];
    if (threadIdx.x < NBINS) sh[threadIdx.x] = 0;
    __syncthreads();
#pragma unroll
    for (int b = 0; b < NBINS; b++)
        if (cnt[b]) atomicAdd(&sh[b], cnt[b]);
    __syncthreads();
    if (threadIdx.x < NBINS && sh[threadIdx.x])
        atomicAdd(&ws_u[8 + m * NBINS + threadIdx.x], sh[threadIdx.x]);
}

__global__ void k_wg(const unsigned* __restrict__ ws_u, float* __restrict__ ws_f) {
    if (threadIdx.x == 0 && blockIdx.x == 0) {
        float e[4];
        for (int m = 0; m < 4; m++) {
            float N = (m < 2) ? (float)(1024 * 1024) : (float)(3 * 1024);
            float s = 0.0f;
            for (int b = 0; b < NBINS; b++) {
                float p = __fdiv_rn((float)ws_u[8 + m * NBINS + b], N);
                if (p > 0.0f) s += p * logf(p);
            }
            e[m] = -s;
        }
        const float API = (float)(0.4 / M_PI);
        ws_f[48] = API * atanf(500.0f * (e[0] - e[1])) + 0.5f;
        ws_f[49] = API * atanf(500.0f * (e[2] - e[3])) + 0.5f;
    }
}

#define BM 64
#define BN 64
#define BK 16
#define LDP (BM + 4)

// pu0 GEMM: out[i][j] = combine( sigmoid( sum_k |Pi-Pj|[i][k]*W[j][k] + bias[j] ) )
__global__ __launch_bounds__(256) void k_gemm_pu(const float* __restrict__ Pi,
                                                 const float* __restrict__ Pj,
                                                 const float* __restrict__ W,
                                                 const float* __restrict__ bias,
                                                 const float* __restrict__ wgp,
                                                 float* __restrict__ out) {
    __shared__ float As[BK][LDP];
    __shared__ float Bs[BK][LDP];
    const int t = threadIdx.x, tx = t & 15, ty = t >> 4;
    const int bi = blockIdx.y, bj = blockIdx.x;
    const int K = 1024, LD = 1024;
    float acc[4][4] = {};
    for (int k0 = 0; k0 < K; k0 += BK) {
#pragma unroll
        for (int l = 0; l < 4; l++) {
            int idx = t + l * 256;
            int i = idx >> 4, k = idx & 15;
            int ga = (bi * BM + i) * LD + k0 + k;
            As[k][i] = fabsf(Pi[ga] - Pj[ga]);
            Bs[k][i] = W[(bj * BN + i) * LD + k0 + k];
        }
        __syncthreads();
#pragma unroll
        for (int k = 0; k < BK; k++) {
            float4 av = *(const float4*)&As[k][ty * 4];
            float4 bv = *(const float4*)&Bs[k][tx * 4];
            float a[4] = {av.x, av.y, av.z, av.w};
            float b[4] = {bv.x, bv.y, bv.z, bv.w};
#pragma unroll
            for (int ii = 0; ii < 4; ii++)
#pragma unroll
                for (int jj = 0; jj < 4; jj++)
                    acc[ii][jj] = fmaf(a[ii], b[jj], acc[ii][jj]);
        }
        __syncthreads();
    }
    float wg = *wgp;
#pragma unroll
    for (int ii = 0; ii < 4; ii++) {
        int i = bi * BM + ty * 4 + ii;
#pragma unroll
        for (int jj = 0; jj < 4; jj++) {
            int j = bj * BN + tx * 4 + jj;
            float s = acc[ii][jj] + bias[j];
            float wl = 1.0f / (1.0f + expf(-s));
            float w = wg * wl + (1.0f - wg);
            float a = Pi[i * LD + j], b = Pj[i * LD + j];
            out[i * LD + j] = a * w + b * (1.0f - w);
        }
    }
}

// h partial GEMM: part[ks][b][c] = sum_{k in chunk ks} x0[b][k]*pu0[c][k]
// grid (16 j-tiles, 8 k-splits)
__global__ __launch_bounds__(256) void k_gemm_h(const float* __restrict__ X,
                                                const float* __restrict__ PU,
                                                float* __restrict__ part) {
    __shared__ float As[BK][LDP];
    __shared__ float Bs[BK][LDP];
    const int t = threadIdx.x, tx = t & 15, ty = t >> 4;
    const int bj = blockIdx.x, ks = blockIdx.y;
    const int XROW = 512 * 1024;  // x[b][0][k] stride between b
    float acc[4][4] = {};
    for (int kk = 0; kk < 128; kk += BK) {
        int k0 = ks * 128 + kk;
#pragma unroll
        for (int l = 0; l < 4; l++) {
            int idx = t + l * 256;
            int i = idx >> 4, k = idx & 15;
            As[k][i] = X[i * XROW + k0 + k];
            Bs[k][i] = PU[(bj * BN + i) * 1024 + k0 + k];
        }
        __syncthreads();
#pragma unroll
        for (int k = 0; k < BK; k++) {
            float4 av = *(const float4*)&As[k][ty * 4];
            float4 bv = *(const float4*)&Bs[k][tx * 4];
            float a[4] = {av.x, av.y, av.z, av.w};
            float b[4] = {bv.x, bv.y, bv.z, bv.w};
#pragma unroll
            for (int ii = 0; ii < 4; ii++)
#pragma unroll
                for (int jj = 0; jj < 4; jj++)
                    acc[ii][jj] = fmaf(a[ii], b[jj], acc[ii][jj]);
        }
        __syncthreads();
    }
#pragma unroll
    for (int ii = 0; ii < 4; ii++) {
        int b = ty * 4 + ii;
#pragma unroll
        for (int jj = 0; jj < 4; jj++) {
            int c = bj * BN + tx * 4 + jj;
            part[(ks * 64 + b) * 1024 + c] = acc[ii][jj];
        }
    }
}

__global__ void k_h_reduce(const float* __restrict__ part, const float* __restrict__ bias,
                           float* __restrict__ h) {
    int idx = blockIdx.x * blockDim.x + threadIdx.x;  // 65536
    int b = idx >> 10, c = idx & 1023;
    float s = 0.0f;
#pragma unroll
    for (int ks = 0; ks < 8; ks++) s += part[(ks * 64 + b) * 1024 + c];
    h[idx] = tanhf(s + bias[c]);
}

// pu1 (M=3): block handles 64 c-columns; 4 threads per c split K
__global__ __launch_bounds__(256) void k_pu1(const float* __restrict__ bow,
                                             const float* __restrict__ gow,
                                             const float* __restrict__ oaw,
                                             const float* __restrict__ oab,
                                             const float* __restrict__ wgp,
                                             float* __restrict__ pu1) {
    __shared__ float D[3][1024];
    __shared__ float P[3][4][64];
    int t = threadIdx.x;
    for (int idx = t; idx < 3072; idx += 256)
        D[idx >> 10][idx & 1023] = fabsf(bow[idx] - gow[idx]);
    __syncthreads();
    int c = blockIdx.x * 64 + (t & 63);
    int kp = t >> 6;  // 0..3
    float a0 = 0.f, a1 = 0.f, a2 = 0.f;
    for (int k = kp * 256; k < kp * 256 + 256; k += 4) {
        float4 wv = *(const float4*)&oaw[c * 1024 + k];
        float4 d0 = *(const float4*)&D[0][k];
        float4 d1 = *(const float4*)&D[1][k];
        float4 d2 = *(const float4*)&D[2][k];
        a0 += d0.x * wv.x + d0.y * wv.y + d0.z * wv.z + d0.w * wv.w;
        a1 += d1.x * wv.x + d1.y * wv.y + d1.z * wv.z + d1.w * wv.w;
        a2 += d2.x * wv.x + d2.y * wv.y + d2.z * wv.z + d2.w * wv.w;
    }
    P[0][kp][t & 63] = a0;
    P[1][kp][t & 63] = a1;
    P[2][kp][t & 63] = a2;
    __syncthreads();
    if (t < 192) {
        int r = t >> 6, cc = t & 63;
        int c2 = blockIdx.x * 64 + cc;
        float s = P[r][0][cc] + P[r][1][cc] + P[r][2][cc] + P[r][3][cc] + oab[c2];
        float wl = 1.0f / (1.0f + expf(-s));
        float wg = *wgp;
        float w = wg * wl + (1.0f - wg);
        pu1[r * 1024 + c2] = bow[r * 1024 + c2] * w + gow[r * 1024 + c2] * (1.0f - w);
    }
}

// out[b][l] = sum_k h[b][k]*pu1[l][k] + bo[l]; one block (64 lanes) per b
__global__ void k_out(const float* __restrict__ h, const float* __restrict__ pu1,
                      const float* __restrict__ bo, float* __restrict__ out) {
    int b = blockIdx.x, lane = threadIdx.x;
    float hv[16];
#pragma unroll
    for (int m = 0; m < 16; m++) hv[m] = h[b * 1024 + lane + m * 64];
#pragma unroll
    for (int l = 0; l < 3; l++) {
        float s = 0.0f;
#pragma unroll
        for (int m = 0; m < 16; m++) s += hv[m] * pu1[l * 1024 + lane + m * 64];
        for (int off = 32; off; off >>= 1) s += __shfl_down(s, off);
        if (lane == 0) out[b * 3 + l] = s + bo[l];
    }
}

extern "C" void kernel_launch(void* const* d_in, const int* in_sizes, int n_in,
                              void* d_out, int out_size, void* d_ws, size_t ws_size,
                              hipStream_t stream) {
    const float* x   = (const float*)d_in[0];
    const float* bdw = (const float*)d_in[1];
    const float* bdb = (const float*)d_in[2];
    const float* bow = (const float*)d_in[3];
    const float* bob = (const float*)d_in[4];
    const float* gdw = (const float*)d_in[5];
    const float* gow = (const float*)d_in[6];
    const float* daw = (const float*)d_in[7];
    const float* dab = (const float*)d_in[8];
    const float* oaw = (const float*)d_in[9];
    const float* oab = (const float*)d_in[10];
    float* out = (float*)d_out;

    unsigned* ws_u = (unsigned*)d_ws;
    float* ws_f = (float*)d_ws;
    float* pu0  = ws_f + 64;
    float* part = pu0 + 1024 * 1024;
    float* h    = part + 8 * 64 * 1024;
    float* pu1  = h + 64 * 1024;

    k_init<<<1, 64, 0, stream>>>(ws_u);
    k_minmax<<<dim3(64, 4), 256, 0, stream>>>(bdw, gdw, bow, gow, ws_u);
    k_hist<<<dim3(64, 4), 256, 0, stream>>>(bdw, gdw, bow, gow, ws_u);
    k_wg<<<1, 64, 0, stream>>>(ws_u, ws_f);
    k_gemm_pu<<<dim3(16, 16), 256, 0, stream>>>(bdw, gdw, daw, dab, ws_f + 48, pu0);
    k_pu1<<<16, 256, 0, stream>>>(bow, gow, oaw, oab, ws_f + 49, pu1);
    k_gemm_h<<<dim3(16, 8), 256, 0, stream>>>(x, pu0, part);
    k_h_reduce<<<256, 256, 0, stream>>>(part, bdb, h);
    k_out<<<64, 64, 0, stream>>>(h, pu1, bob, out);
}

// Round 2
// 107.344 us; speedup vs baseline: 1.4486x; 1.4486x over previous
//
#include <hip/hip_runtime.h>
#include <hip/hip_bf16.h>
#include <math.h>

// ---------------------------------------------------------------------------
// UnitingModelForNLP: h = tanh(x0 @ pu0^T + bdb); out = h @ pu1^T + bob
// pu = unite(p_i, p_j, W, b):
//   w_local = sigmoid(|p_i-p_j| @ W^T + b)
//   w_global = 0.4/pi * atan(500*(H(p_i)-H(p_j))) + 0.5   (10-bin histogram entropy)
//   w = wg*w_local + (1-wg);  pu = p_i*w + p_j*(1-w)
//
// This round: big GEMMs moved to bf16 MFMA (16x16x32), staged via
// global_load_lds(16B) into XOR-swizzled LDS (conflict-free ds_read_b128).
// Entropy path stays exact-f32 (500x amplified -> must match numpy bins).
//
// Workspace (bytes from d_ws):
//   [0..255]    counters: u32 minmax(8) + hist(40) + wg at float slot 48/49
//   +1024:      Db   bf16 1024x1024  (|bdw-gdw|)          2 MB
//   +:          Wb   bf16 1024x1024  (daw)                2 MB
//   +:          x0b  bf16 64x1024                         128 KB
//   +:          pu0b bf16 1024x1024                       2 MB
//   +:          part f32 8x64x1024                        2 MB
//   +:          h    f32 64x1024                          256 KB
//   +:          pu1  f32 3x1024                           12 KB
// ---------------------------------------------------------------------------

#define NBINS 10

typedef short bf8v __attribute__((ext_vector_type(8)));
typedef float f32x4 __attribute__((ext_vector_type(4)));

static __device__ __forceinline__ unsigned enc_f(float x) {
    unsigned u = __float_as_uint(x);
    return (u & 0x80000000u) ? ~u : (u | 0x80000000u);
}
static __device__ __forceinline__ float dec_f(unsigned u) {
    u = (u & 0x80000000u) ? (u & 0x7FFFFFFFu) : ~u;
    return __uint_as_float(u);
}
static __device__ __forceinline__ unsigned short f2bf(float f) {
    __hip_bfloat16 h = __float2bfloat16(f);
    return __builtin_bit_cast(unsigned short, h);
}

#define GL2LDS(gp, lp) __builtin_amdgcn_global_load_lds(                       \
    (__attribute__((address_space(1))) void*)(gp),                             \
    (__attribute__((address_space(3))) void*)(lp), 16, 0, 0)

__global__ void k_init(unsigned* ws_u) {
    int t = threadIdx.x;
    if (t < 8)  ws_u[t] = (t & 1) ? 0u : 0xFFFFFFFFu;
    if (t >= 8 && t < 48) ws_u[t] = 0u;
}

// Convert to bf16: Db=|bdw-gdw|, Wb=daw, x0b=x[:,0,:]
__global__ __launch_bounds__(256) void k_conv(const float* __restrict__ bdw,
                                              const float* __restrict__ gdw,
                                              const float* __restrict__ daw,
                                              const float* __restrict__ x,
                                              unsigned short* __restrict__ Db,
                                              unsigned short* __restrict__ Wb,
                                              unsigned short* __restrict__ x0b) {
    int idx = blockIdx.x * 256 + threadIdx.x;   // 1024 blocks -> 262144 threads
    {
        float4 a = ((const float4*)bdw)[idx];
        float4 b = ((const float4*)gdw)[idx];
        float4 w = ((const float4*)daw)[idx];
        ushort4 d, ww;
        d.x = f2bf(fabsf(a.x - b.x)); d.y = f2bf(fabsf(a.y - b.y));
        d.z = f2bf(fabsf(a.z - b.z)); d.w = f2bf(fabsf(a.w - b.w));
        ww.x = f2bf(w.x); ww.y = f2bf(w.y); ww.z = f2bf(w.z); ww.w = f2bf(w.w);
        ((ushort4*)Db)[idx] = d;
        ((ushort4*)Wb)[idx] = ww;
    }
    if (idx < 16384) {  // 64 rows x 256 float4
        int b = idx >> 8, k4 = idx & 255;
        float4 v = *(const float4*)&x[(size_t)b * 512 * 1024 + k4 * 4];
        ushort4 o;
        o.x = f2bf(v.x); o.y = f2bf(v.y); o.z = f2bf(v.z); o.w = f2bf(v.w);
        ((ushort4*)x0b)[idx] = o;
    }
}

__global__ void k_minmax(const float* __restrict__ a0, const float* __restrict__ a1,
                         const float* __restrict__ a2, const float* __restrict__ a3,
                         unsigned* __restrict__ ws_u) {
    int m = blockIdx.y;
    const float* p = (m == 0) ? a0 : (m == 1) ? a1 : (m == 2) ? a2 : a3;
    int n = (m < 2) ? 1024 * 1024 : 3 * 1024;
    float lo = INFINITY, hi = -INFINITY;
    for (int i = blockIdx.x * blockDim.x + threadIdx.x; i < n; i += gridDim.x * blockDim.x) {
        float v = p[i];
        lo = fminf(lo, v);
        hi = fmaxf(hi, v);
    }
    for (int off = 32; off; off >>= 1) {
        lo = fminf(lo, __shfl_down(lo, off));
        hi = fmaxf(hi, __shfl_down(hi, off));
    }
    __shared__ float slo[4], shi[4];
    int wid = threadIdx.x >> 6;
    if ((threadIdx.x & 63) == 0) { slo[wid] = lo; shi[wid] = hi; }
    __syncthreads();
    if (threadIdx.x == 0) {
        for (int w = 1; w < (int)(blockDim.x >> 6); w++) { lo = fminf(lo, slo[w]); hi = fmaxf(hi, shi[w]); }
        atomicMin(&ws_u[2 * m], enc_f(lo));
        atomicMax(&ws_u[2 * m + 1], enc_f(hi));
    }
}

__global__ void k_hist(const float* __restrict__ a0, const float* __restrict__ a1,
                       const float* __restrict__ a2, const float* __restrict__ a3,
                       unsigned* __restrict__ ws_u) {
    int m = blockIdx.y;
    const float* p = (m == 0) ? a0 : (m == 1) ? a1 : (m == 2) ? a2 : a3;
    int n = (m < 2) ? 1024 * 1024 : 3 * 1024;
    float lo = dec_f(ws_u[2 * m]);
    float hi = dec_f(ws_u[2 * m + 1]);
    float scale = __fdiv_rn(__fsub_rn(hi, lo), 10.0f);
    float lower[NBINS], upper[NBINS];
#pragma unroll
    for (int b = 0; b < NBINS; b++) {
        lower[b] = __fadd_rn(lo, __fmul_rn((float)b, scale));
        upper[b] = __fadd_rn(lower[b], scale);
    }
    unsigned cnt[NBINS] = {};
    for (int i = blockIdx.x * blockDim.x + threadIdx.x; i < n; i += gridDim.x * blockDim.x) {
        float v = p[i];
#pragma unroll
        for (int b = 0; b < NBINS; b++)
            if (v >= lower[b] && v < upper[b]) cnt[b]++;
    }
    __shared__ unsigned sh[NBINS];
    if (threadIdx.x < NBINS) sh[threadIdx.x] = 0;
    __syncthreads();
#pragma unroll
    for (int b = 0; b < NBINS; b++)
        if (cnt[b]) atomicAdd(&sh[b], cnt[b]);
    __syncthreads();
    if (threadIdx.x < NBINS && sh[threadIdx.x])
        atomicAdd(&ws_u[8 + m * NBINS + threadIdx.x], sh[threadIdx.x]);
}

__global__ void k_wg(const unsigned* __restrict__ ws_u, float* __restrict__ ws_f) {
    if (threadIdx.x == 0 && blockIdx.x == 0) {
        float e[4];
        for (int m = 0; m < 4; m++) {
            float N = (m < 2) ? (float)(1024 * 1024) : (float)(3 * 1024);
            float s = 0.0f;
            for (int b = 0; b < NBINS; b++) {
                float p = __fdiv_rn((float)ws_u[8 + m * NBINS + b], N);
                if (p > 0.0f) s += p * logf(p);
            }
            e[m] = -s;
        }
        const float API = (float)(0.4 / M_PI);
        ws_f[48] = API * atanf(500.0f * (e[0] - e[1])) + 0.5f;
        ws_f[49] = API * atanf(500.0f * (e[2] - e[3])) + 0.5f;
    }
}

// ---------------------------------------------------------------------------
// MFMA tiles. 64x64 tile, BK=32, 4 waves (2x2), each wave 32x32 = 2x2 frags.
// LDS tile layout: [64 rows][4 slots of 16B], slot s holds k-block
// kg = s ^ ((row>>1)&3)  (XOR swizzle -> 2-way max bank aliasing = free).
// global_load_lds writes linearly; swizzle applied on the global SOURCE addr.
// ---------------------------------------------------------------------------

static __device__ __forceinline__ void stage_tile(const unsigned short* __restrict__ src,
                                                  short* lds_tile, int t, int row0, int k0) {
    int r = t >> 2, s = t & 3;
    int kg = s ^ ((r >> 1) & 3);
    const unsigned short* g = src + (size_t)(row0 + r) * 1024 + k0 + kg * 8;
    GL2LDS(g, lds_tile + t * 8);
}

static __device__ __forceinline__ int frag_off(int row, int k8) {
    return row * 4 + (k8 ^ ((row >> 1) & 3));  // in 8-element (16B) units
}

// pu0: C[i][j] = combine(sigmoid(sum_k Db[i][k]*Wb[j][k] + dab[j])) -> pu0b bf16
__global__ __launch_bounds__(256) void k_gemm_pu_mfma(
    const unsigned short* __restrict__ Db, const unsigned short* __restrict__ Wb,
    const float* __restrict__ bdw, const float* __restrict__ gdw,
    const float* __restrict__ dab, const float* __restrict__ wgp,
    unsigned short* __restrict__ pu0b) {
    __shared__ short As[2][64 * 32];
    __shared__ short Bs[2][64 * 32];
    const int t = threadIdx.x;
    const int lane = t & 63, w = t >> 6;
    const int wr = w >> 1, wc = w & 1;
    const int lr = lane & 15, k8 = lane >> 4;
    const int bi = blockIdx.y, bj = blockIdx.x;

    f32x4 acc[2][2] = {};

    stage_tile(Db, As[0], t, bi * 64, 0);
    stage_tile(Wb, Bs[0], t, bj * 64, 0);
    int cur = 0;
    const int NT = 32;
    for (int tt = 0; tt < NT; ++tt) {
        __syncthreads();  // drains vmcnt -> staged tile visible; waves done with other buf
        if (tt + 1 < NT) {
            stage_tile(Db, As[cur ^ 1], t, bi * 64, (tt + 1) * 32);
            stage_tile(Wb, Bs[cur ^ 1], t, bj * 64, (tt + 1) * 32);
        }
        const bf8v* Av = (const bf8v*)As[cur];
        const bf8v* Bv = (const bf8v*)Bs[cur];
        bf8v a0 = Av[frag_off(wr * 32 + lr, k8)];
        bf8v a1 = Av[frag_off(wr * 32 + 16 + lr, k8)];
        bf8v b0 = Bv[frag_off(wc * 32 + lr, k8)];
        bf8v b1 = Bv[frag_off(wc * 32 + 16 + lr, k8)];
        acc[0][0] = __builtin_amdgcn_mfma_f32_16x16x32_bf16(a0, b0, acc[0][0], 0, 0, 0);
        acc[0][1] = __builtin_amdgcn_mfma_f32_16x16x32_bf16(a0, b1, acc[0][1], 0, 0, 0);
        acc[1][0] = __builtin_amdgcn_mfma_f32_16x16x32_bf16(a1, b0, acc[1][0], 0, 0, 0);
        acc[1][1] = __builtin_amdgcn_mfma_f32_16x16x32_bf16(a1, b1, acc[1][1], 0, 0, 0);
        cur ^= 1;
    }

    float wg = *wgp;
#pragma unroll
    for (int mi = 0; mi < 2; mi++)
#pragma unroll
        for (int mj = 0; mj < 2; mj++)
#pragma unroll
            for (int r = 0; r < 4; r++) {
                int i = bi * 64 + wr * 32 + mi * 16 + k8 * 4 + r;
                int j = bj * 64 + wc * 32 + mj * 16 + lr;
                float s = acc[mi][mj][r] + dab[j];
                float wl = 1.0f / (1.0f + expf(-s));
                float ww = wg * wl + (1.0f - wg);
                float o = bdw[i * 1024 + j] * ww + gdw[i * 1024 + j] * (1.0f - ww);
                pu0b[i * 1024 + j] = f2bf(o);
            }
}

// h partials: part[ks][m][c] = sum_{k in 128-chunk ks} x0b[m][k]*pu0b[c][k]
__global__ __launch_bounds__(256) void k_gemm_h_mfma(
    const unsigned short* __restrict__ x0b, const unsigned short* __restrict__ pu0b,
    float* __restrict__ part) {
    __shared__ short As[2][64 * 32];
    __shared__ short Bs[2][64 * 32];
    const int t = threadIdx.x;
    const int lane = t & 63, w = t >> 6;
    const int wr = w >> 1, wc = w & 1;
    const int lr = lane & 15, k8 = lane >> 4;
    const int bj = blockIdx.x, ks = blockIdx.y;

    f32x4 acc[2][2] = {};

    stage_tile(x0b, As[0], t, 0, ks * 128);
    stage_tile(pu0b, Bs[0], t, bj * 64, ks * 128);
    int cur = 0;
    const int NT = 4;
    for (int tt = 0; tt < NT; ++tt) {
        __syncthreads();
        if (tt + 1 < NT) {
            stage_tile(x0b, As[cur ^ 1], t, 0, ks * 128 + (tt + 1) * 32);
            stage_tile(pu0b, Bs[cur ^ 1], t, bj * 64, ks * 128 + (tt + 1) * 32);
        }
        const bf8v* Av = (const bf8v*)As[cur];
        const bf8v* Bv = (const bf8v*)Bs[cur];
        bf8v a0 = Av[frag_off(wr * 32 + lr, k8)];
        bf8v a1 = Av[frag_off(wr * 32 + 16 + lr, k8)];
        bf8v b0 = Bv[frag_off(wc * 32 + lr, k8)];
        bf8v b1 = Bv[frag_off(wc * 32 + 16 + lr, k8)];
        acc[0][0] = __builtin_amdgcn_mfma_f32_16x16x32_bf16(a0, b0, acc[0][0], 0, 0, 0);
        acc[0][1] = __builtin_amdgcn_mfma_f32_16x16x32_bf16(a0, b1, acc[0][1], 0, 0, 0);
        acc[1][0] = __builtin_amdgcn_mfma_f32_16x16x32_bf16(a1, b0, acc[1][0], 0, 0, 0);
        acc[1][1] = __builtin_amdgcn_mfma_f32_16x16x32_bf16(a1, b1, acc[1][1], 0, 0, 0);
        cur ^= 1;
    }

#pragma unroll
    for (int mi = 0; mi < 2; mi++)
#pragma unroll
        for (int mj = 0; mj < 2; mj++)
#pragma unroll
            for (int r = 0; r < 4; r++) {
                int m = wr * 32 + mi * 16 + k8 * 4 + r;
                int c = bj * 64 + wc * 32 + mj * 16 + lr;
                part[(size_t)(ks * 64 + m) * 1024 + c] = acc[mi][mj][r];
            }
}

__global__ void k_h_reduce(const float* __restrict__ part, const float* __restrict__ bias,
                           float* __restrict__ h) {
    int idx = blockIdx.x * blockDim.x + threadIdx.x;  // 65536
    int b = idx >> 10, c = idx & 1023;
    float s = 0.0f;
#pragma unroll
    for (int ks = 0; ks < 8; ks++) s += part[(ks * 64 + b) * 1024 + c];
    h[idx] = tanhf(s + bias[c]);
}

// pu1 (M=3)
__global__ __launch_bounds__(256) void k_pu1(const float* __restrict__ bow,
                                             const float* __restrict__ gow,
                                             const float* __restrict__ oaw,
                                             const float* __restrict__ oab,
                                             const float* __restrict__ wgp,
                                             float* __restrict__ pu1) {
    __shared__ float D[3][1024];
    __shared__ float P[3][4][64];
    int t = threadIdx.x;
    for (int idx = t; idx < 3072; idx += 256)
        D[idx >> 10][idx & 1023] = fabsf(bow[idx] - gow[idx]);
    __syncthreads();
    int c = blockIdx.x * 64 + (t & 63);
    int kp = t >> 6;
    float a0 = 0.f, a1 = 0.f, a2 = 0.f;
    for (int k = kp * 256; k < kp * 256 + 256; k += 4) {
        float4 wv = *(const float4*)&oaw[c * 1024 + k];
        float4 d0 = *(const float4*)&D[0][k];
        float4 d1 = *(const float4*)&D[1][k];
        float4 d2 = *(const float4*)&D[2][k];
        a0 += d0.x * wv.x + d0.y * wv.y + d0.z * wv.z + d0.w * wv.w;
        a1 += d1.x * wv.x + d1.y * wv.y + d1.z * wv.z + d1.w * wv.w;
        a2 += d2.x * wv.x + d2.y * wv.y + d2.z * wv.z + d2.w * wv.w;
    }
    P[0][kp][t & 63] = a0;
    P[1][kp][t & 63] = a1;
    P[2][kp][t & 63] = a2;
    __syncthreads();
    if (t < 192) {
        int r = t >> 6, cc = t & 63;
        int c2 = blockIdx.x * 64 + cc;
        float s = P[r][0][cc] + P[r][1][cc] + P[r][2][cc] + P[r][3][cc] + oab[c2];
        float wl = 1.0f / (1.0f + expf(-s));
        float wg = *wgp;
        float w = wg * wl + (1.0f - wg);
        pu1[r * 1024 + c2] = bow[r * 1024 + c2] * w + gow[r * 1024 + c2] * (1.0f - w);
    }
}

__global__ void k_out(const float* __restrict__ h, const float* __restrict__ pu1,
                      const float* __restrict__ bo, float* __restrict__ out) {
    int b = blockIdx.x, lane = threadIdx.x;
    float hv[16];
#pragma unroll
    for (int m = 0; m < 16; m++) hv[m] = h[b * 1024 + lane + m * 64];
#pragma unroll
    for (int l = 0; l < 3; l++) {
        float s = 0.0f;
#pragma unroll
        for (int m = 0; m < 16; m++) s += hv[m] * pu1[l * 1024 + lane + m * 64];
        for (int off = 32; off; off >>= 1) s += __shfl_down(s, off);
        if (lane == 0) out[b * 3 + l] = s + bo[l];
    }
}

extern "C" void kernel_launch(void* const* d_in, const int* in_sizes, int n_in,
                              void* d_out, int out_size, void* d_ws, size_t ws_size,
                              hipStream_t stream) {
    const float* x   = (const float*)d_in[0];
    const float* bdw = (const float*)d_in[1];
    const float* bdb = (const float*)d_in[2];
    const float* bow = (const float*)d_in[3];
    const float* bob = (const float*)d_in[4];
    const float* gdw = (const float*)d_in[5];
    const float* gow = (const float*)d_in[6];
    const float* daw = (const float*)d_in[7];
    const float* dab = (const float*)d_in[8];
    const float* oaw = (const float*)d_in[9];
    const float* oab = (const float*)d_in[10];
    float* out = (float*)d_out;

    char* base = (char*)d_ws;
    unsigned* ws_u = (unsigned*)base;
    float* ws_f = (float*)base;
    unsigned short* Db   = (unsigned short*)(base + 1024);
    unsigned short* Wb   = Db + 1024 * 1024;
    unsigned short* x0b  = Wb + 1024 * 1024;
    unsigned short* pu0b = x0b + 64 * 1024;
    float* part = (float*)(pu0b + 1024 * 1024);
    float* h    = part + 8 * 64 * 1024;
    float* pu1  = h + 64 * 1024;

    k_init<<<1, 64, 0, stream>>>(ws_u);
    k_conv<<<1024, 256, 0, stream>>>(bdw, gdw, daw, x, Db, Wb, x0b);
    k_minmax<<<dim3(64, 4), 256, 0, stream>>>(bdw, gdw, bow, gow, ws_u);
    k_hist<<<dim3(64, 4), 256, 0, stream>>>(bdw, gdw, bow, gow, ws_u);
    k_wg<<<1, 64, 0, stream>>>(ws_u, ws_f);
    k_gemm_pu_mfma<<<dim3(16, 16), 256, 0, stream>>>(Db, Wb, bdw, gdw, dab, ws_f + 48, pu0b);
    k_pu1<<<16, 256, 0, stream>>>(bow, gow, oaw, oab, ws_f + 49, pu1);
    k_gemm_h_mfma<<<dim3(16, 8), 256, 0, stream>>>(x0b, pu0b, part);
    k_h_reduce<<<256, 256, 0, stream>>>(part, bdb, h);
    k_out<<<64, 64, 0, stream>>>(h, pu1, bob, out);
}